// Round 2
// baseline (219.250 us; speedup 1.0000x reference)
//
#include <hip/hip_runtime.h>
#include <hip/hip_bf16.h>
#include <math.h>

#define N 8192
#define D 1024
#define BM 256
#define BK 64
#define NTIL 32                         // 8192/256
#define NBLK 528                        // 32*33/2 lower-tri tiles
#define ITERS 8                         // 16 K-tiles / 2 per iteration

typedef __bf16 bf16_t;
typedef bf16_t bf16x4 __attribute__((ext_vector_type(4)));
typedef bf16_t bf16x8 __attribute__((ext_vector_type(8)));
typedef float f32x4 __attribute__((ext_vector_type(4)));

// ---------------------------------------------------------------------------
// Kernel 1: L2-normalize each row of the fp32 embeddings, cast to bf16.
// ---------------------------------------------------------------------------
__global__ __launch_bounds__(256) void norm_cast(const float* __restrict__ in,
                                                 bf16_t* __restrict__ out) {
    const int row = blockIdx.x;
    const int tid = threadIdx.x;
    const float4 v = ((const float4*)(in + (size_t)row * D))[tid];
    float ss = v.x * v.x + v.y * v.y + v.z * v.z + v.w * v.w;
    #pragma unroll
    for (int off = 32; off >= 1; off >>= 1) ss += __shfl_xor(ss, off, 64);
    __shared__ float red[4];
    const int wave = tid >> 6, lane = tid & 63;
    if (lane == 0) red[wave] = ss;
    __syncthreads();
    const float tot = red[0] + red[1] + red[2] + red[3];
    const float scale = 1.0f / fmaxf(sqrtf(tot), 1e-12f);
    bf16x4 o;
    o[0] = (bf16_t)(v.x * scale);
    o[1] = (bf16_t)(v.y * scale);
    o[2] = (bf16_t)(v.z * scale);
    o[3] = (bf16_t)(v.w * scale);
    ((bf16x4*)(out + (size_t)row * D))[tid] = o;
}

// ---------------------------------------------------------------------------
// Kernel 2: fused symmetric  C = E·E^T / T -> exp -> masked row+col sums.
// 256x256 tiles, BK=64, 8 waves (2M x 4N), 8-phase schedule (2 K-tiles/iter),
// counted vmcnt(4) at phases 4/8, double-buffered LDS = exactly 128 KiB.
// No other VMEM ops inside the counted window (labels are read in epilogue).
// LDS swizzle: physical 16B unit = logical ^ (row&7); staging keeps the LDS
// destination linear (global_load_lds requirement) and inverse-permutes the
// GLOBAL source address; frag reads apply the same XOR.
// ---------------------------------------------------------------------------
__global__ __launch_bounds__(512, 2) void gemm_fused(const bf16_t* __restrict__ E,
                                                     const int* __restrict__ labels,
                                                     float* __restrict__ sumExp,
                                                     float* __restrict__ posSum) {
    __shared__ bf16_t As[2][2][128 * 64];   // [buf][half(rows 0-127 / 128-255)][...]
    __shared__ bf16_t Bs[2][2][128 * 64];   // [buf][half(cols 0-127 / 128-255)][...]
    // total static LDS: 131072 B == the verified 128 KiB template size

    // XCD-aware bijective swizzle (528 % 8 == 0): 66 consecutive tiles per XCD
    const int b0 = blockIdx.x;
    const int b  = (b0 & 7) * (NBLK / 8) + (b0 >> 3);

    // triangular decode: b -> (ti >= tj)
    int ti = (int)((sqrtf(8.0f * (float)b + 1.0f) - 1.0f) * 0.5f);
    while ((ti + 1) * (ti + 2) / 2 <= b) ++ti;
    while (ti * (ti + 1) / 2 > b) --ti;
    const int tj = b - ti * (ti + 1) / 2;
    const bool isDiag = (ti == tj);

    const int tid  = threadIdx.x;
    const int wave = tid >> 6;
    const int lane = tid & 63;
    const int lr   = lane & 15;
    const int q    = lane >> 4;
    const int wm   = wave >> 2;     // 0..1 : row half
    const int wn   = wave & 3;      // 0..3 : 64-col strip
    const int rowStart = ti * BM;
    const int colStart = tj * BM;

    f32x4 acc[8][4];
    #pragma unroll
    for (int m = 0; m < 8; ++m)
        #pragma unroll
        for (int n = 0; n < 4; ++n) acc[m][n] = {0.f, 0.f, 0.f, 0.f};

    // ---- staging geometry: thread covers linear 16B units (p*512 + tid) of a
    // 128x64 half-tile; phys unit u -> row r=u>>3, logical unit (u&7)^(r&7).
    const int r0  = tid >> 3;                    // 0..63 (second load adds 64 rows)
    const int lu0 = (tid & 7) ^ (r0 & 7);
    const char* gA = (const char*)(E + (size_t)rowStart * D) + (size_t)r0 * (D * 2) + lu0 * 16;
    const char* gB = (const char*)(E + (size_t)colStart * D) + (size_t)r0 * (D * 2) + lu0 * 16;

    #define STAGE_A(buf, h, kb) do {                                                     \
        const char* g0_ = gA + (size_t)(h) * (128 * 2048) + (kb);                        \
        char* l0_ = (char*)&As[buf][h][0] + wave * 1024;                                 \
        __builtin_amdgcn_global_load_lds((const __attribute__((address_space(1))) void*)g0_, \
            (__attribute__((address_space(3))) void*)l0_, 16, 0, 0);                     \
        __builtin_amdgcn_global_load_lds(                                                \
            (const __attribute__((address_space(1))) void*)(g0_ + 64 * 2048),            \
            (__attribute__((address_space(3))) void*)(l0_ + 8192), 16, 0, 0);            \
    } while (0)
    #define STAGE_B(buf, h, kb) do {                                                     \
        const char* g0_ = gB + (size_t)(h) * (128 * 2048) + (kb);                        \
        char* l0_ = (char*)&Bs[buf][h][0] + wave * 1024;                                 \
        __builtin_amdgcn_global_load_lds((const __attribute__((address_space(1))) void*)g0_, \
            (__attribute__((address_space(3))) void*)l0_, 16, 0, 0);                     \
        __builtin_amdgcn_global_load_lds(                                                \
            (const __attribute__((address_space(1))) void*)(g0_ + 64 * 2048),            \
            (__attribute__((address_space(3))) void*)(l0_ + 8192), 16, 0, 0);            \
    } while (0)

    // ---- frag-read bases. A: local row rr = m*16+lr, logical unit u0 = k*4+q,
    // phys = u0 ^ (lr&7) (row offsets are multiples of 8, XOR term unchanged).
    const int su0 = ((0 + q) ^ (lane & 7)) * 16;     // k = 0
    const int su1 = ((4 + q) ^ (lane & 7)) * 16;     // k = 1
    const char* rA0 = (const char*)&As[0][wm][0] + lr * 128;
    const char* rA1 = (const char*)&As[1][wm][0] + lr * 128;
    const char* rB0 = (const char*)&Bs[0][wn >> 1][0] + (wn & 1) * 8192 + lr * 128;
    const char* rB1 = (const char*)&Bs[1][wn >> 1][0] + (wn & 1) * 8192 + lr * 128;

    #define LD_A4(DST, RBASE, MOFFB, SU) do {                                            \
        _Pragma("unroll")                                                                \
        for (int m_ = 0; m_ < 4; ++m_)                                                   \
            DST[m_] = *(const bf16x8*)((RBASE) + (MOFFB) + m_ * 2048 + (SU));            \
    } while (0)
    #define LD_B4(DST, RBASE, SU) do {                                                   \
        _Pragma("unroll")                                                                \
        for (int n_ = 0; n_ < 4; ++n_)                                                   \
            DST[n_] = *(const bf16x8*)((RBASE) + n_ * 2048 + (SU));                      \
    } while (0)
    #define MFMA_QUAD(AF, BF, MO) do {                                                   \
        _Pragma("unroll")                                                                \
        for (int m_ = 0; m_ < 4; ++m_) {                                                 \
            _Pragma("unroll")                                                            \
            for (int n_ = 0; n_ < 4; ++n_)                                               \
                acc[(MO) + m_][n_] = __builtin_amdgcn_mfma_f32_16x16x32_bf16(            \
                    AF[m_], BF[n_], acc[(MO) + m_][n_], 0, 0, 0);                        \
        }                                                                                \
    } while (0)
    #define PHASE_MID() do {                                                             \
        __builtin_amdgcn_s_barrier();                                                    \
        asm volatile("s_waitcnt lgkmcnt(0)");                                            \
        __builtin_amdgcn_sched_barrier(0);                                               \
        __builtin_amdgcn_s_setprio(1);                                                   \
    } while (0)
    #define PHASE_END() do {                                                             \
        __builtin_amdgcn_s_setprio(0);                                                   \
        __builtin_amdgcn_s_barrier();                                                    \
    } while (0)

    bf16x8 a0[4], a1[4], bq0[4], bq1[4];

    // ---- prologue: buf0 (K-tile 0) fully + buf1.B (K-tile 1). 12 loads;
    // vmcnt(4) -> buf0's 8 landed, buf1.B's 4 stay in flight.
    STAGE_B(0, 0, 0);  STAGE_B(0, 1, 0);
    STAGE_A(0, 0, 0);  STAGE_A(0, 1, 0);
    STAGE_B(1, 0, 128); STAGE_B(1, 1, 128);
    asm volatile("s_waitcnt vmcnt(4)" ::: "memory");
    __builtin_amdgcn_sched_barrier(0);
    __builtin_amdgcn_s_barrier();

    #pragma unroll 1
    for (int it = 0; it < ITERS; ++it) {
        const bool lastIt = (it == ITERS - 1);
        const int kb1 = (2 * it + 1) * 128;   // buf1's K-tile (byte col offset)
        const int kb2 = (2 * it + 2) * 128;   // next buf0 K-tile
        const int kb3 = (2 * it + 3) * 128;   // next buf1 K-tile

        // phase 1: buf0, m0-3, k0 | stage buf1.A h0 (this iter's second tile)
        LD_A4(a0, rA0, 0, su0);
        LD_B4(bq0, rB0, su0);
        STAGE_A(1, 0, kb1);
        PHASE_MID();
        MFMA_QUAD(a0, bq0, 0);
        PHASE_END();

        // phase 2: buf0, m0-3, k1 | stage buf1.A h1
        LD_A4(a1, rA0, 0, su1);
        LD_B4(bq1, rB0, su1);
        STAGE_A(1, 1, kb1);
        PHASE_MID();
        MFMA_QUAD(a1, bq1, 0);
        PHASE_END();

        // phase 3: buf0, m4-7, k0 | stage buf0.B h0 (K-tile 2it+2)
        LD_A4(a0, rA0, 8192, su0);
        if (!lastIt) STAGE_B(0, 0, kb2);
        PHASE_MID();
        MFMA_QUAD(a0, bq0, 4);
        PHASE_END();

        // phase 4: buf0, m4-7, k1 | stage buf0.B h1 | counted vmcnt:
        // waits the oldest 8 = buf1.A (ph1/2) + buf1.B (prev ph7/8 or prologue)
        LD_A4(a1, rA0, 8192, su1);
        if (!lastIt) {
            STAGE_B(0, 1, kb2);
            asm volatile("s_waitcnt vmcnt(4)" ::: "memory");
        } else {
            asm volatile("s_waitcnt vmcnt(0)" ::: "memory");
        }
        __builtin_amdgcn_sched_barrier(0);
        PHASE_MID();
        MFMA_QUAD(a1, bq1, 4);
        PHASE_END();

        // phase 5: buf1, m0-3, k0 | stage buf0.A h0
        LD_A4(a0, rA1, 0, su0);
        LD_B4(bq0, rB1, su0);
        if (!lastIt) STAGE_A(0, 0, kb2);
        PHASE_MID();
        MFMA_QUAD(a0, bq0, 0);
        PHASE_END();

        // phase 6: buf1, m0-3, k1 | stage buf0.A h1
        LD_A4(a1, rA1, 0, su1);
        LD_B4(bq1, rB1, su1);
        if (!lastIt) STAGE_A(0, 1, kb2);
        PHASE_MID();
        MFMA_QUAD(a1, bq1, 0);
        PHASE_END();

        // phase 7: buf1, m4-7, k0 | stage buf1.B h0 (K-tile 2it+3)
        LD_A4(a0, rA1, 8192, su0);
        if (!lastIt) STAGE_B(1, 0, kb3);
        PHASE_MID();
        MFMA_QUAD(a0, bq0, 4);
        PHASE_END();

        // phase 8: buf1, m4-7, k1 | stage buf1.B h1 | counted vmcnt:
        // waits the oldest 8 = buf0.B (ph3/4) + buf0.A (ph5/6)
        LD_A4(a1, rA1, 8192, su1);
        if (!lastIt) {
            STAGE_B(1, 1, kb3);
            asm volatile("s_waitcnt vmcnt(4)" ::: "memory");
            __builtin_amdgcn_sched_barrier(0);
        }
        PHASE_MID();
        MFMA_QUAD(a1, bq1, 4);
        PHASE_END();
    }

    // ---- epilogue: C/D layout col=lane&15, row=q*4+e (m89/m91).
    // Labels read straight from global (L2-resident, once per block).
    const float invT = 1.0f / 0.07f;
    int lc[4];
    #pragma unroll
    for (int n = 0; n < 4; ++n)
        lc[n] = labels[colStart + wn * 64 + n * 16 + lr];

    float colAll[4] = {0.f, 0.f, 0.f, 0.f};
    float colPos[4] = {0.f, 0.f, 0.f, 0.f};
    #pragma unroll
    for (int m = 0; m < 8; ++m) {
        #pragma unroll
        for (int e = 0; e < 4; ++e) {
            const int rloc = wm * 128 + m * 16 + q * 4 + e;
            const int gi   = rowStart + rloc;
            const int li   = labels[gi];
            float s_all = 0.f, s_pos = 0.f;
            #pragma unroll
            for (int n = 0; n < 4; ++n) {
                const int cloc = wn * 64 + n * 16 + lr;
                const int gj   = colStart + cloc;
                const float v  = __expf(acc[m][n][e] * invT);
                const bool same = (lc[n] == li);
                s_all += v;
                if (same && gi != gj) s_pos += v;
                if (!isDiag) {            // wave-uniform branch
                    colAll[n] += v;       // gi != gj guaranteed off-diagonal
                    if (same) colPos[n] += v;
                }
            }
            #pragma unroll
            for (int off = 1; off < 16; off <<= 1) {
                s_all += __shfl_xor(s_all, off, 64);
                s_pos += __shfl_xor(s_pos, off, 64);
            }
            if (lr == 0) {
                atomicAdd(&sumExp[gi], s_all);
                atomicAdd(&posSum[gi], s_pos);
            }
        }
    }
    if (!isDiag) {
        #pragma unroll
        for (int n = 0; n < 4; ++n) {
            float a = colAll[n], p = colPos[n];
            a += __shfl_xor(a, 16, 64);  a += __shfl_xor(a, 32, 64);
            p += __shfl_xor(p, 16, 64);  p += __shfl_xor(p, 32, 64);
            if (q == 0) {
                const int gj = colStart + wn * 64 + n * 16 + lr;
                atomicAdd(&sumExp[gj], a);
                atomicAdd(&posSum[gj], p);
            }
        }
    }
}

// ---------------------------------------------------------------------------
// Kernel 3: loss_i = log(sumExp_i / posSum_i); out = mean(loss).
// ---------------------------------------------------------------------------
__global__ __launch_bounds__(1024) void finalize(const float* __restrict__ sumExp,
                                                 const float* __restrict__ posSum,
                                                 float* __restrict__ out) {
    const int tid = threadIdx.x;
    float s = 0.f;
    #pragma unroll
    for (int i = tid; i < N; i += 1024)
        s += __logf(sumExp[i] / posSum[i]);
    #pragma unroll
    for (int off = 32; off >= 1; off >>= 1) s += __shfl_xor(s, off, 64);
    __shared__ float red[16];
    if ((tid & 63) == 0) red[tid >> 6] = s;
    __syncthreads();
    if (tid == 0) {
        float t = 0.f;
        #pragma unroll
        for (int i = 0; i < 16; ++i) t += red[i];
        out[0] = t / (float)N;
    }
}

extern "C" void kernel_launch(void* const* d_in, const int* in_sizes, int n_in,
                              void* d_out, int out_size, void* d_ws, size_t ws_size,
                              hipStream_t stream) {
    const float* emb    = (const float*)d_in[0];
    const int*   labels = (const int*)d_in[1];
    float* out = (float*)d_out;

    // ws layout: [sumExp: N floats][posSum: N floats][EN: N*D bf16]
    float*  sumExp = (float*)d_ws;
    float*  posSum = sumExp + N;
    bf16_t* EN     = (bf16_t*)((char*)d_ws + (size_t)2 * N * sizeof(float));

    hipMemsetAsync(d_ws, 0, (size_t)2 * N * sizeof(float), stream);

    norm_cast<<<N, 256, 0, stream>>>(emb, EN);

    gemm_fused<<<NBLK, 512, 0, stream>>>(EN, labels, sumExp, posSum);

    finalize<<<1, 1024, 0, stream>>>(sumExp, posSum, out);
}